// Round 2
// baseline (404.518 us; speedup 1.0000x reference)
//
#include <hip/hip_runtime.h>

typedef __attribute__((ext_vector_type(4))) float f32x4;
typedef __attribute__((ext_vector_type(8))) short s16x8;
typedef __attribute__((ext_vector_type(4))) short s16x4;

constexpr int T_SEQ = 2048;
constexpr int D = 64;        // head channels
constexpr int H = 16;        // heads
constexpr int QBLK = 64;     // q rows per block (16 per wave)
constexpr int KVBLK = 64;    // kv rows per iteration
constexpr int NTHREADS = 256;

// round-to-nearest-even f32 -> bf16
__device__ __forceinline__ unsigned short f2bf(float f) {
  unsigned int u = __builtin_bit_cast(unsigned int, f);
  u += 0x7FFFu + ((u >> 16) & 1u);
  return (unsigned short)(u >> 16);
}

// XOR swizzle for [rows][64] bf16 tiles (128B rows): spreads column-slice
// ds_read_b128 across banks. Bijective within each 8-row stripe; preserves
// 8B/16B alignment (only touches byte-address bits 4..6).
__device__ __forceinline__ int swz(int row, int colByte) {
  return row * 128 + (colByte ^ ((row & 7) << 4));
}

__global__ __launch_bounds__(NTHREADS, 2)
void attn_kernel(const float* __restrict__ qkv, const float* __restrict__ mask,
                 float* __restrict__ out) {
  __shared__ __align__(16) char smem[33024];
  char* Qc = smem;                 // [64 q][64 c] bf16 swz, 8KB
  char* Kc = smem + 8192;          // [64 s][64 c] bf16 swz, 8KB
  char* Vc = smem + 16384;         // [64 c][64 s] bf16 swz, 8KB
  char* Pc = smem + 24576;         // 4 waves x [16 q][64 s] bf16 swz, 8KB
  float* maskS = (float*)(smem + 32768);  // 64 f32
  float* Ost = (float*)smem;       // [64 c][68] f32 (aliases Q/K after loop)

  const int tid = threadIdx.x;
  const int qt = blockIdx.x;       // q-tile
  const int bh = blockIdx.y;       // batch*H + head
  const int b = bh >> 4, h = bh & 15;

  const size_t headBase = ((size_t)b * (3 * H * D) + (size_t)h * (3 * D)) * T_SEQ;
  const float* gQ = qkv + headBase;
  const float* gK = gQ + (size_t)D * T_SEQ;
  const float* gV = gQ + (size_t)(2 * D) * T_SEQ;
  // reference quirk: jnp.tile(mask,(H,1)) -> row (b*H+h) % N == h % 4
  const float* gM = mask + (size_t)(bh & 3) * T_SEQ;

  // ---- stage Q transposed [q][c], scaled by 1/sqrt(D) folded into Q ----
  {
    const int sb = (tid & 15) * 4;   // q within tile
    const int cb = (tid >> 4) * 4;   // channel
    const int q0 = qt * QBLK;
    f32x4 r[4];
#pragma unroll
    for (int j = 0; j < 4; ++j)
      r[j] = *(const f32x4*)(gQ + (size_t)(cb + j) * T_SEQ + q0 + sb);
#pragma unroll
    for (int i = 0; i < 4; ++i) {
      s16x4 w;
#pragma unroll
      for (int j = 0; j < 4; ++j) w[j] = (short)f2bf(r[j][i] * 0.125f);
      *(s16x4*)(Qc + swz(sb + i, 2 * cb)) = w;
    }
  }
  __syncthreads();

  const int wave = tid >> 6, lane = tid & 63;
  const int lg = lane >> 4, lid = lane & 15;

  // Q A-fragments: A[i=q][k=c], lane i=lid, k = 8*lg + e (+32 per ko)
  s16x8 aq[2];
#pragma unroll
  for (int ko = 0; ko < 2; ++ko)
    aq[ko] = *(const s16x8*)(Qc + swz(wave * 16 + lid, 16 * lg + 64 * ko));

  float m0[4], l0[4];
  f32x4 accO[4];
#pragma unroll
  for (int r = 0; r < 4; ++r) { m0[r] = -1e30f; l0[r] = 0.0f; }
#pragma unroll
  for (int ct = 0; ct < 4; ++ct) accO[ct] = (f32x4){0.f, 0.f, 0.f, 0.f};

  char* Pw = Pc + wave * 2048;

  for (int s0 = 0; s0 < T_SEQ; s0 += KVBLK) {
    __syncthreads();  // previous iteration's K/V reads complete
    // ---- stage K transposed [s][c] ----
    {
      const int sb = (tid & 15) * 4;
      const int cb = (tid >> 4) * 4;
      f32x4 r[4];
#pragma unroll
      for (int j = 0; j < 4; ++j)
        r[j] = *(const f32x4*)(gK + (size_t)(cb + j) * T_SEQ + s0 + sb);
#pragma unroll
      for (int i = 0; i < 4; ++i) {
        s16x4 w;
#pragma unroll
        for (int j = 0; j < 4; ++j) w[j] = (short)f2bf(r[j][i]);
        *(s16x4*)(Kc + swz(sb + i, 2 * cb)) = w;
      }
    }
    // ---- stage V natural [c][s] ----
    {
      const int c = tid >> 2;
      const int sbase = (tid & 3) * 16;
      f32x4 r[4];
#pragma unroll
      for (int j = 0; j < 4; ++j)
        r[j] = *(const f32x4*)(gV + (size_t)c * T_SEQ + s0 + sbase + 4 * j);
      s16x8 w0, w1;
#pragma unroll
      for (int j = 0; j < 8; ++j) w0[j] = (short)f2bf(r[j >> 2][j & 3]);
#pragma unroll
      for (int j = 0; j < 8; ++j) w1[j] = (short)f2bf(r[2 + (j >> 2)][j & 3]);
      *(s16x8*)(Vc + swz(c, 2 * sbase)) = w0;
      *(s16x8*)(Vc + swz(c, 2 * sbase + 16)) = w1;
    }
    if (tid < 64) maskS[tid] = gM[s0 + tid];
    __syncthreads();

    // ---- S = Q^T K  (A=Q^T frag, B=K frag; same contiguous-k convention) ----
    f32x4 accS[4];
#pragma unroll
    for (int nt = 0; nt < 4; ++nt) accS[nt] = (f32x4){0.f, 0.f, 0.f, 0.f};
#pragma unroll
    for (int ko = 0; ko < 2; ++ko) {
#pragma unroll
      for (int nt = 0; nt < 4; ++nt) {
        s16x8 bk = *(const s16x8*)(Kc + swz(nt * 16 + lid, 16 * lg + 64 * ko));
        accS[nt] = __builtin_amdgcn_mfma_f32_16x16x32_bf16(aq[ko], bk, accS[nt], 0, 0, 0);
      }
    }

    // ---- online softmax (C layout: row q = 4*lg + r, col s = nt*16 + lid) ----
    float tm[4];
#pragma unroll
    for (int r = 0; r < 4; ++r)
      tm[r] = fmaxf(fmaxf(accS[0][r], accS[1][r]), fmaxf(accS[2][r], accS[3][r]));
#pragma unroll
    for (int off = 1; off < 16; off <<= 1) {
#pragma unroll
      for (int r = 0; r < 4; ++r)
        tm[r] = fmaxf(tm[r], __shfl_xor(tm[r], off, 64));
    }
    float p[4][4], sc[4], rs[4];
#pragma unroll
    for (int r = 0; r < 4; ++r) {
      float nm = fmaxf(m0[r], tm[r]);
      sc[r] = __expf(m0[r] - nm);
      m0[r] = nm;
    }
#pragma unroll
    for (int nt = 0; nt < 4; ++nt) {
#pragma unroll
      for (int r = 0; r < 4; ++r) p[nt][r] = __expf(accS[nt][r] - m0[r]);
    }
#pragma unroll
    for (int r = 0; r < 4; ++r)
      rs[r] = (p[0][r] + p[1][r]) + (p[2][r] + p[3][r]);
#pragma unroll
    for (int off = 1; off < 16; off <<= 1) {
#pragma unroll
      for (int r = 0; r < 4; ++r) rs[r] += __shfl_xor(rs[r], off, 64);
    }
#pragma unroll
    for (int r = 0; r < 4; ++r) l0[r] = l0[r] * sc[r] + rs[r];
#pragma unroll
    for (int ct = 0; ct < 4; ++ct) {
#pragma unroll
      for (int r = 0; r < 4; ++r) accO[ct][r] *= sc[r];
    }

    // ---- P (masked, denominator stays unmasked) -> per-wave LDS bf16 ----
#pragma unroll
    for (int nt = 0; nt < 4; ++nt) {
      const float mk = maskS[nt * 16 + lid];
#pragma unroll
      for (int r = 0; r < 4; ++r)
        *(short*)(Pw + swz(4 * lg + r, 2 * (nt * 16 + lid))) =
            (short)f2bf(p[nt][r] * mk);
    }

    // ---- O += P V^T  (A=P frag from LDS, B=V frag [c][s] contiguous-s) ----
    // per-wave DS ops are in-order: no barrier needed for Pw write->read
#pragma unroll
    for (int ko = 0; ko < 2; ++ko) {
      s16x8 ap = *(const s16x8*)(Pw + swz(lid, 16 * lg + 64 * ko));
#pragma unroll
      for (int ct = 0; ct < 4; ++ct) {
        s16x8 bv = *(const s16x8*)(Vc + swz(ct * 16 + lid, 16 * lg + 64 * ko));
        accO[ct] = __builtin_amdgcn_mfma_f32_16x16x32_bf16(ap, bv, accO[ct], 0, 0, 0);
      }
    }
  }

  __syncthreads();  // all V reads done before Ost aliases Q/K/V regions
  // O tile -> LDS [c][q] (pad 68 keeps 16B alignment + conflict-free)
#pragma unroll
  for (int r = 0; r < 4; ++r) {
    const float rcp = 1.0f / l0[r];
#pragma unroll
    for (int ct = 0; ct < 4; ++ct)
      Ost[(ct * 16 + lid) * 68 + wave * 16 + 4 * lg + r] = accO[ct][r] * rcp;
  }
  __syncthreads();
  // coalesced output: out[b][h*64 + c][qt*64 + t]
  {
    const int c = tid >> 2;
    const int tb = (tid & 3) * 16;
    float* orow = out + ((size_t)(b * (H * D) + h * D + c)) * T_SEQ + qt * QBLK + tb;
#pragma unroll
    for (int j = 0; j < 4; ++j)
      *(f32x4*)(orow + 4 * j) = *(const f32x4*)(Ost + c * 68 + tb + 4 * j);
  }
}

extern "C" void kernel_launch(void* const* d_in, const int* in_sizes, int n_in,
                              void* d_out, int out_size, void* d_ws, size_t ws_size,
                              hipStream_t stream) {
  const float* qkv = (const float*)d_in[0];
  const float* mask = (const float*)d_in[1];
  float* out = (float*)d_out;
  dim3 grid(T_SEQ / QBLK, 64);  // 32 q-tiles x 64 batch-heads
  attn_kernel<<<grid, NTHREADS, 0, stream>>>(qkv, mask, out);
}

// Round 3
// 313.589 us; speedup vs baseline: 1.2900x; 1.2900x over previous
//
#include <hip/hip_runtime.h>

typedef __attribute__((ext_vector_type(4))) float f32x4;
typedef __attribute__((ext_vector_type(8))) short s16x8;
typedef __attribute__((ext_vector_type(4))) short s16x4;

constexpr int T_SEQ = 2048;
constexpr int D = 64;        // head channels
constexpr int H = 16;        // heads
constexpr int QBLK = 128;    // q rows per block (16 per wave, 8 waves)
constexpr int KVBLK = 64;    // kv rows per iteration
constexpr int NTHREADS = 512;

// round-to-nearest-even f32 -> bf16
__device__ __forceinline__ unsigned short f2bf(float f) {
  unsigned int u = __builtin_bit_cast(unsigned int, f);
  u += 0x7FFFu + ((u >> 16) & 1u);
  return (unsigned short)(u >> 16);
}

// XOR swizzle for [rows][64] bf16 tiles (128B rows). Bijective per 8-row
// stripe; touches byte bits 4..6 only -> preserves 8B/16B alignment.
__device__ __forceinline__ int swz(int row, int colByte) {
  return row * 128 + (colByte ^ ((row & 7) << 4));
}

__global__ __launch_bounds__(NTHREADS, 4)
void attn_kernel(const float* __restrict__ qkv, const float* __restrict__ mask,
                 float* __restrict__ out) {
  __shared__ __align__(16) char smem[33024];
  // phase 1: Qstage [128 q][64 c] bf16 swz (16 KB, dies after frag extract)
  // phase 2: Kc [64 s][64 c] @0 (8K); Vc [64 c][64 s] @8K; Pc 8x2KB @16K;
  //          maskS f32[64] @32768
  char* Qc = smem;
  char* Kc = smem;
  char* Vc = smem + 8192;
  char* Pc = smem + 16384;
  float* maskS = (float*)(smem + 32768);

  const int tid = threadIdx.x;
  const int qt = blockIdx.x;       // q-tile (128 q each)
  const int bh = blockIdx.y;       // batch*H + head
  const int b = bh >> 4, h = bh & 15;

  const size_t headBase = ((size_t)b * (3 * H * D) + (size_t)h * (3 * D)) * T_SEQ;
  const float* gQ = qkv + headBase;
  const float* gK = gQ + (size_t)D * T_SEQ;
  const float* gV = gQ + (size_t)(2 * D) * T_SEQ;
  // reference quirk: jnp.tile(mask,(H,1)) -> row (b*H+h) % N == h % 4
  const float* gM = mask + (size_t)(bh & 3) * T_SEQ;

  // ---- stage Q transposed [q][c], 1/sqrt(D) folded in (512 thr, 16/thr) ----
  {
    const int sb = (tid & 31) * 4;   // q within tile
    const int cb = (tid >> 5) * 4;   // channel
    const int q0 = qt * QBLK;
    f32x4 r[4];
#pragma unroll
    for (int j = 0; j < 4; ++j)
      r[j] = *(const f32x4*)(gQ + (size_t)(cb + j) * T_SEQ + q0 + sb);
#pragma unroll
    for (int i = 0; i < 4; ++i) {
      s16x4 w;
#pragma unroll
      for (int j = 0; j < 4; ++j) w[j] = (short)f2bf(r[j][i] * 0.125f);
      *(s16x4*)(Qc + swz(sb + i, 2 * cb)) = w;
    }
  }
  __syncthreads();

  const int wave = tid >> 6, lane = tid & 63;
  const int lg = lane >> 4, lid = lane & 15;

  // Q B-fragments for swapped QK^T: lane holds Q[q=wave*16+lid][k-slot 8lg+e]
  s16x8 aq[2];
#pragma unroll
  for (int ko = 0; ko < 2; ++ko)
    aq[ko] = *(const s16x8*)(Qc + swz(wave * 16 + lid, 16 * lg + 64 * ko));

  // per-lane softmax state for q = qt*128 + wave*16 + lid
  float m0 = -1e30f, l0 = 0.0f;
  f32x4 accO[4];   // accO[ct][r] = O^T[c=16ct+4lg+r][q=lid]
#pragma unroll
  for (int ct = 0; ct < 4; ++ct) accO[ct] = (f32x4){0.f, 0.f, 0.f, 0.f};

  char* Pw = Pc + wave * 2048;     // [16 q=lid][64 s] bf16 swz

  for (int s0 = 0; s0 < T_SEQ; s0 += KVBLK) {
    __syncthreads();  // previous iteration's K/V/Q reads complete
    if (tid < 256) {
      // ---- stage K transposed [s][c] (4s x 4c per thread) ----
      const int sb = (tid & 15) * 4;
      const int cb = (tid >> 4) * 4;
      f32x4 r[4];
#pragma unroll
      for (int j = 0; j < 4; ++j)
        r[j] = *(const f32x4*)(gK + (size_t)(cb + j) * T_SEQ + s0 + sb);
#pragma unroll
      for (int i = 0; i < 4; ++i) {
        s16x4 w;
#pragma unroll
        for (int j = 0; j < 4; ++j) w[j] = (short)f2bf(r[j][i]);
        *(s16x4*)(Kc + swz(sb + i, 2 * cb)) = w;
      }
    } else {
      // ---- stage V natural [c][s] (1c x 16s per thread) ----
      const int t = tid - 256;
      const int c = t >> 2;
      const int sbase = (t & 3) * 16;
      f32x4 r[4];
#pragma unroll
      for (int j = 0; j < 4; ++j)
        r[j] = *(const f32x4*)(gV + (size_t)c * T_SEQ + s0 + sbase + 4 * j);
      s16x8 w0, w1;
#pragma unroll
      for (int j = 0; j < 8; ++j) w0[j] = (short)f2bf(r[j >> 2][j & 3]);
#pragma unroll
      for (int j = 0; j < 8; ++j) w1[j] = (short)f2bf(r[2 + (j >> 2)][j & 3]);
      *(s16x8*)(Vc + swz(c, 2 * sbase)) = w0;
      *(s16x8*)(Vc + swz(c, 2 * sbase + 16)) = w1;
      if (tid >= 448) maskS[tid - 448] = gM[s0 + tid - 448];
    }
    __syncthreads();

    // ---- S^T = mfma(K, Q): C[s=16nt+4lg+r][q=lid] ----
    f32x4 accST[4];
#pragma unroll
    for (int nt = 0; nt < 4; ++nt) accST[nt] = (f32x4){0.f, 0.f, 0.f, 0.f};
#pragma unroll
    for (int ko = 0; ko < 2; ++ko) {
#pragma unroll
      for (int nt = 0; nt < 4; ++nt) {
        s16x8 ak = *(const s16x8*)(Kc + swz(nt * 16 + lid, 16 * lg + 64 * ko));
        accST[nt] = __builtin_amdgcn_mfma_f32_16x16x32_bf16(ak, aq[ko], accST[nt], 0, 0, 0);
      }
    }

    // ---- per-lane online softmax (lane owns q=lid; s spread over lg) ----
    float tm = accST[0][0];
#pragma unroll
    for (int nt = 0; nt < 4; ++nt) {
#pragma unroll
      for (int r = 0; r < 4; ++r) tm = fmaxf(tm, accST[nt][r]);
    }
    tm = fmaxf(tm, __shfl_xor(tm, 16));
    tm = fmaxf(tm, __shfl_xor(tm, 32));
    // T13 defer-rescale: only rescale when max grew by > 8
    if (!__all(tm - m0 <= 8.0f)) {
      const float nm = fmaxf(m0, tm);
      const float sc = __expf(m0 - nm);
      m0 = nm;
      l0 *= sc;
#pragma unroll
      for (int ct = 0; ct < 4; ++ct) {
#pragma unroll
        for (int r = 0; r < 4; ++r) accO[ct][r] *= sc;
      }
    }
    float p[4][4], rs = 0.0f;
#pragma unroll
    for (int nt = 0; nt < 4; ++nt) {
#pragma unroll
      for (int r = 0; r < 4; ++r) {
        p[nt][r] = __expf(accST[nt][r] - m0);
        rs += p[nt][r];
      }
    }
    rs += __shfl_xor(rs, 16);
    rs += __shfl_xor(rs, 32);
    l0 += rs;   // denominator unmasked (ref: softmax before mask)

    // ---- P (masked) -> per-wave LDS, 4x 8B contiguous writes ----
#pragma unroll
    for (int nt = 0; nt < 4; ++nt) {
      const f32x4 mk = *(const f32x4*)&maskS[16 * nt + 4 * lg];
      s16x4 w;
#pragma unroll
      for (int r = 0; r < 4; ++r) w[r] = (short)f2bf(p[nt][r] * mk[r]);
      *(s16x4*)(Pw + swz(lid, 32 * nt + 8 * lg)) = w;
    }

    // ---- O^T += mfma(V, P): C[c=16ct+4lg+r][q=lid] ----
    // per-wave DS in-order: no barrier needed for Pw write->read
#pragma unroll
    for (int ko = 0; ko < 2; ++ko) {
      s16x8 bp = *(const s16x8*)(Pw + swz(lid, 64 * ko + 16 * lg));
#pragma unroll
      for (int ct = 0; ct < 4; ++ct) {
        s16x8 av = *(const s16x8*)(Vc + swz(ct * 16 + lid, 64 * ko + 16 * lg));
        accO[ct] = __builtin_amdgcn_mfma_f32_16x16x32_bf16(av, bp, accO[ct], 0, 0, 0);
      }
    }
  }

  // ---- epilogue: direct stores, lanes lid=0..15 give 64B segments ----
  const float rcp = 1.0f / l0;
  const int qcol = qt * QBLK + wave * 16 + lid;
#pragma unroll
  for (int ct = 0; ct < 4; ++ct) {
#pragma unroll
    for (int r = 0; r < 4; ++r) {
      const int c = 16 * ct + 4 * lg + r;
      out[((size_t)(b * (H * D) + h * D + c)) * T_SEQ + qcol] = accO[ct][r] * rcp;
    }
  }
}

extern "C" void kernel_launch(void* const* d_in, const int* in_sizes, int n_in,
                              void* d_out, int out_size, void* d_ws, size_t ws_size,
                              hipStream_t stream) {
  const float* qkv = (const float*)d_in[0];
  const float* mask = (const float*)d_in[1];
  float* out = (float*)d_out;
  dim3 grid(T_SEQ / QBLK, 64);  // 16 q-tiles x 64 batch-heads
  attn_kernel<<<grid, NTHREADS, 0, stream>>>(qkv, mask, out);
}

// Round 5
// 277.078 us; speedup vs baseline: 1.4599x; 1.1318x over previous
//
#include <hip/hip_runtime.h>
#include <hip/hip_bf16.h>

typedef __attribute__((ext_vector_type(4))) float f32x4;
typedef __attribute__((ext_vector_type(2))) float f32x2;
typedef __attribute__((ext_vector_type(8))) short s16x8;
typedef __attribute__((ext_vector_type(4))) short s16x4;

constexpr int T_SEQ = 2048;
constexpr int D = 64;        // head channels
constexpr int H = 16;        // heads
constexpr int QBLK = 128;    // q rows per block (16 per wave, 8 waves)
constexpr int KVBLK = 64;    // kv rows per iteration
constexpr int NTHREADS = 512;
constexpr float LOG2E = 1.44269504088896340736f;

// native f32->bf16 (RNE): compiler emits v_cvt_pk_bf16_f32 for pairs (m240)
__device__ __forceinline__ short f2bf(float f) {
  return (short)__builtin_bit_cast(unsigned short, __float2bfloat16(f));
}

__device__ __forceinline__ float fast_exp2(float x) {
#if __has_builtin(__builtin_amdgcn_exp2f)
  return __builtin_amdgcn_exp2f(x);
#else
  return exp2f(x);
#endif
}

// XOR swizzle for [rows][64] bf16 tiles (128B rows). Bijective per 8-row
// stripe; touches byte bits 4..6 only -> preserves 8B/16B alignment.
__device__ __forceinline__ int swz(int row, int colByte) {
  return row * 128 + (colByte ^ ((row & 7) << 4));
}

__global__ __launch_bounds__(NTHREADS, 6)
void attn_kernel(const float* __restrict__ qkv, const float* __restrict__ mask,
                 float* __restrict__ out) {
  __shared__ __align__(16) char smem[40960];
  // phase 1: Qstage [128 q][64 c] bf16 swz @0 (16 KB, dies after frag extract)
  // steady:  Kc [64 s][64 c] @0 (8K); Vc [64 c][64 s] @8K; Pc 8x2KB @16K;
  //          maskLds f32[2048] @32768 (8K)  -> 40960 B total (4 blocks/CU max)
  char* Qc = smem;
  char* Kc = smem;
  char* Vc = smem + 8192;
  char* Pc = smem + 16384;
  float* maskLds = (float*)(smem + 32768);

  const int tid = threadIdx.x;
  // T1: XCD-aware swizzle — all 16 q-tiles of one bh land on one XCD's L2.
  int flat = blockIdx.y * 16 + blockIdx.x;       // 0..1023, dispatch xcd=flat&7
  flat = (flat & 7) * 128 + (flat >> 3);          // bijection (1024 = 8*128)
  const int qt = flat & 15;
  const int bh = flat >> 4;
  const int b = bh >> 4, h = bh & 15;

  const size_t headBase = ((size_t)b * (3 * H * D) + (size_t)h * (3 * D)) * T_SEQ;
  const float* gQ = qkv + headBase;
  const float* gK = gQ + (size_t)D * T_SEQ;
  const float* gV = gQ + (size_t)(2 * D) * T_SEQ;
  // reference quirk: jnp.tile(mask,(H,1)) -> row (b*H+h) % N == h % 4
  const float* gM = mask + (size_t)(bh & 3) * T_SEQ;

  // ---- prologue: preload mask row (8KB) + stage Q transposed [q][c] ----
  *(f32x4*)&maskLds[tid * 4] = *(const f32x4*)&gM[tid * 4];
  {
    const int sb = (tid & 31) * 4;   // q within tile
    const int cb = (tid >> 5) * 4;   // channel
    const int q0 = qt * QBLK;
    const float qscale = 0.125f * LOG2E;  // 1/sqrt(64) * log2(e) folded in
    f32x4 r[4];
#pragma unroll
    for (int j = 0; j < 4; ++j)
      r[j] = *(const f32x4*)(gQ + (size_t)(cb + j) * T_SEQ + q0 + sb);
#pragma unroll
    for (int i = 0; i < 4; ++i) {
      s16x4 w;
#pragma unroll
      for (int j = 0; j < 4; ++j) w[j] = f2bf(r[j][i] * qscale);
      *(s16x4*)(Qc + swz(sb + i, 2 * cb)) = w;
    }
  }
  __syncthreads();

  const int wave = tid >> 6, lane = tid & 63;
  const int lg = lane >> 4, lid = lane & 15;

  // Q B-fragments for swapped QK^T: lane holds Q[q=wave*16+lid][k-slot 8lg+e]
  s16x8 aq[2];
#pragma unroll
  for (int ko = 0; ko < 2; ++ko)
    aq[ko] = *(const s16x8*)(Qc + swz(wave * 16 + lid, 16 * lg + 64 * ko));

  // per-lane softmax state (log2 domain) for q = qt*128 + wave*16 + lid
  float m0 = -1e30f, l0 = 0.0f;
  f32x4 accO[4];   // accO[ct][r] = O^T[c=16ct+4lg+r][q=lid]
#pragma unroll
  for (int ct = 0; ct < 4; ++ct) accO[ct] = (f32x4){0.f, 0.f, 0.f, 0.f};

  char* Pw = Pc + wave * 2048;     // [16 q=lid][64 s] bf16 swz

  for (int s0 = 0; s0 < T_SEQ; s0 += KVBLK) {
    __syncthreads();  // previous iteration's K/V/Q reads complete
    if (tid < 256) {
      // ---- stage K transposed [s][c]: 2s x 8c per thread, b128 writes ----
      const int sb = 2 * (tid & 31);
      const int cb = 8 * (tid >> 5);
      f32x2 r[8];
#pragma unroll
      for (int j = 0; j < 8; ++j)
        r[j] = *(const f32x2*)(gK + (size_t)(cb + j) * T_SEQ + s0 + sb);
#pragma unroll
      for (int i = 0; i < 2; ++i) {
        s16x8 w;
#pragma unroll
        for (int j = 0; j < 8; ++j) w[j] = f2bf(r[j][i]);
        *(s16x8*)(Kc + swz(sb + i, 2 * cb)) = w;
      }
    } else {
      // ---- stage V natural [c][s], mask folded in (P*mask@V == P@(V.*mask)) ----
      const int t2 = tid - 256;
      const int c = t2 >> 2;
      const int sbase = 16 * (t2 & 3);
      f32x4 r[4], mk[4];
#pragma unroll
      for (int j = 0; j < 4; ++j) {
        r[j] = *(const f32x4*)(gV + (size_t)c * T_SEQ + s0 + sbase + 4 * j);
        mk[j] = *(const f32x4*)&maskLds[s0 + sbase + 4 * j];
      }
      s16x8 w0, w1;
#pragma unroll
      for (int j = 0; j < 8; ++j) w0[j] = f2bf(r[j >> 2][j & 3] * mk[j >> 2][j & 3]);
#pragma unroll
      for (int j = 0; j < 8; ++j)
        w1[j] = f2bf(r[2 + (j >> 2)][j & 3] * mk[2 + (j >> 2)][j & 3]);
      *(s16x8*)(Vc + swz(c, 2 * sbase)) = w0;
      *(s16x8*)(Vc + swz(c, 2 * sbase + 16)) = w1;
    }
    __syncthreads();

    // ---- S^T = mfma(K, Q): C[s=16nt+4lg+r][q=lid], log2-scaled ----
    f32x4 accST[4];
#pragma unroll
    for (int nt = 0; nt < 4; ++nt) accST[nt] = (f32x4){0.f, 0.f, 0.f, 0.f};
    __builtin_amdgcn_s_setprio(1);
#pragma unroll
    for (int ko = 0; ko < 2; ++ko) {
#pragma unroll
      for (int nt = 0; nt < 4; ++nt) {
        s16x8 ak = *(const s16x8*)(Kc + swz(nt * 16 + lid, 16 * lg + 64 * ko));
        accST[nt] = __builtin_amdgcn_mfma_f32_16x16x32_bf16(ak, aq[ko], accST[nt], 0, 0, 0);
      }
    }
    __builtin_amdgcn_s_setprio(0);

    // ---- per-lane online softmax (lane owns q=lid; s spread over lg) ----
    float mx[4];
#pragma unroll
    for (int nt = 0; nt < 4; ++nt)
      mx[nt] = fmaxf(fmaxf(accST[nt][0], accST[nt][1]),
                     fmaxf(accST[nt][2], accST[nt][3]));
    float tm = fmaxf(fmaxf(mx[0], mx[1]), fmaxf(mx[2], mx[3]));
    tm = fmaxf(tm, __shfl_xor(tm, 16));
    tm = fmaxf(tm, __shfl_xor(tm, 32));
    // T13 defer-rescale (log2 domain: 8*log2e)
    if (!__all(tm - m0 <= 11.5416f)) {
      const float nm = fmaxf(m0, tm);
      const float sc = fast_exp2(m0 - nm);
      m0 = nm;
      l0 *= sc;
#pragma unroll
      for (int ct = 0; ct < 4; ++ct) {
#pragma unroll
        for (int r = 0; r < 4; ++r) accO[ct][r] *= sc;
      }
    }
    float p[4][4], ps[4];
#pragma unroll
    for (int nt = 0; nt < 4; ++nt) {
#pragma unroll
      for (int r = 0; r < 4; ++r) p[nt][r] = fast_exp2(accST[nt][r] - m0);
      ps[nt] = (p[nt][0] + p[nt][1]) + (p[nt][2] + p[nt][3]);
    }
    float rs = (ps[0] + ps[1]) + (ps[2] + ps[3]);
    rs += __shfl_xor(rs, 16);
    rs += __shfl_xor(rs, 32);
    l0 += rs;   // denominator unmasked (ref: softmax before mask)

    // ---- P -> per-wave LDS, 4x 8B writes (conflict-free, pk-converts) ----
#pragma unroll
    for (int nt = 0; nt < 4; ++nt) {
      s16x4 w;
#pragma unroll
      for (int r = 0; r < 4; ++r) w[r] = f2bf(p[nt][r]);
      *(s16x4*)(Pw + swz(lid, 32 * nt + 8 * lg)) = w;
    }

    // ---- O^T += mfma(V, P): C[c=16ct+4lg+r][q=lid] ----
    // per-wave DS in-order: no barrier needed for Pw write->read
    __builtin_amdgcn_s_setprio(1);
#pragma unroll
    for (int ko = 0; ko < 2; ++ko) {
      s16x8 bp = *(const s16x8*)(Pw + swz(lid, 64 * ko + 16 * lg));
#pragma unroll
      for (int ct = 0; ct < 4; ++ct) {
        s16x8 av = *(const s16x8*)(Vc + swz(ct * 16 + lid, 64 * ko + 16 * lg));
        accO[ct] = __builtin_amdgcn_mfma_f32_16x16x32_bf16(av, bp, accO[ct], 0, 0, 0);
      }
    }
    __builtin_amdgcn_s_setprio(0);
  }

  // ---- epilogue: direct stores, lanes lid=0..15 give 64B segments ----
  const float rcp = 1.0f / l0;
  const int qcol = qt * QBLK + wave * 16 + lid;
#pragma unroll
  for (int ct = 0; ct < 4; ++ct) {
#pragma unroll
    for (int r = 0; r < 4; ++r) {
      const int c = 16 * ct + 4 * lg + r;
      out[((size_t)(b * (H * D) + h * D + c)) * T_SEQ + qcol] = accO[ct][r] * rcp;
    }
  }
}

extern "C" void kernel_launch(void* const* d_in, const int* in_sizes, int n_in,
                              void* d_out, int out_size, void* d_ws, size_t ws_size,
                              hipStream_t stream) {
  const float* qkv = (const float*)d_in[0];
  const float* mask = (const float*)d_in[1];
  float* out = (float*)d_out;
  dim3 grid(T_SEQ / QBLK, 64);  // 16 q-tiles x 64 batch-heads
  attn_kernel<<<grid, NTHREADS, 0, stream>>>(qkv, mask, out);
}